// Round 9
// baseline (474.193 us; speedup 1.0000x reference)
//
#include <hip/hip_runtime.h>

#define NN 100000
#define EE 1600000
#define DD 64
#define LL 5
#define BN_EPS 1e-5f
#define SLOT 64
#define NTILES (NN / 16)            // 6250 node-tiles of 16
#define TPAD 68                     // padded z/y row stride (floats)
#define NPART ((NN + 255) / 256)    // 391 partitions of 256 nodes
#define PCAP 4608                   // per-partition edge cap (mean 4092, +8 sigma)
#define BIN_CHUNK 4096
#define BIN_BLOCKS ((EE + BIN_CHUNK - 1) / BIN_CHUNK)   // 391

typedef __attribute__((ext_vector_type(8))) short short8;
typedef __attribute__((ext_vector_type(4))) float f32x4;

static __device__ __forceinline__ unsigned short f2bf(float f) {
    union { float f; unsigned u; } v; v.f = f;
    unsigned u = v.u + 0x7fffu + ((v.u >> 16) & 1u);   // RNE
    return (unsigned short)(u >> 16);
}
static __device__ __forceinline__ float bf2f(unsigned short s) {
    union { unsigned u; float f; } v; v.u = ((unsigned)s) << 16;
    return v.f;
}
// unpack low/high bf16 of a u32 (two packed bf16) to f32
static __device__ __forceinline__ float bflo(unsigned u) {
    union { unsigned x; float f; } v; v.x = u << 16; return v.f;
}
static __device__ __forceinline__ float bfhi(unsigned u) {
    union { unsigned x; float f; } v; v.x = u & 0xffff0000u; return v.f;
}
// broadcast slot K within each 8-lane group: lane l <- lane (l & 0x18) | K
// (BitMode swizzle, halves of 32 lanes; groups never straddle a half)
template<int K>
static __device__ __forceinline__ int swz8(int s) {
    return __builtin_amdgcn_ds_swizzle(s, (K << 5) | 0x18);
}

// ---------------------------------------------------------------- pass 1: bin edges
__global__ __launch_bounds__(256) void bin2_kernel(const int* __restrict__ src,
                                                   const int* __restrict__ dst,
                                                   int* __restrict__ pcnt,
                                                   int* __restrict__ part) {
    __shared__ int hist[NPART];
    __shared__ int basep[NPART];
    const int t = threadIdx.x;
    const int e0 = blockIdx.x * BIN_CHUNK;
    const int e1 = min(e0 + BIN_CHUNK, EE);

    for (int i = t; i < NPART; i += 256) hist[i] = 0;
    __syncthreads();
    for (int e = e0 + t; e < e1; e += 256)
        atomicAdd(&hist[dst[e] >> 8], 1);
    __syncthreads();
    for (int i = t; i < NPART; i += 256) {
        int c = hist[i];
        basep[i] = (c > 0) ? atomicAdd(&pcnt[i], c) : 0;
        hist[i] = 0;                           // reuse as cursor
    }
    __syncthreads();
    for (int e = e0 + t; e < e1; e += 256) {
        int d = dst[e];
        int s = src[e];
        int p = d >> 8;
        int pos = basep[p] + atomicAdd(&hist[p], 1);
        if (pos < PCAP) part[p * PCAP + pos] = ((d & 255) << 17) | s;
    }
}

// ---------------------------------------------------------------- pass 2: dense slot table
// ONE-pass (no prefix scan, no second part[] read). Dense layout:
// srtb[node*64 + slot] = src; cnt[node] = deg. Garbage beyond deg is never
// used as an address (gather cndmask's masked slot indices to 0 BEFORE the
// load), so no zero-padding needed.
__global__ __launch_bounds__(256) void csr_kernel(const int* __restrict__ pcnt,
                                                  const int* __restrict__ part,
                                                  int* __restrict__ cnt,
                                                  int* __restrict__ srtb) {
    __shared__ int c256[256];

    const int p = blockIdx.x;
    const int t = threadIdx.x;
    const int M = min(pcnt[p], PCAP);

    c256[t] = 0;
    __syncthreads();
    for (int i = t; i < M; i += 256) {
        int e = part[p * PCAP + i];
        int ld = e >> 17;
        int slot = atomicAdd(&c256[ld], 1);
        if (slot < SLOT) srtb[(((p << 8) + ld) << 6) + slot] = e & 0x1FFFF;
    }
    __syncthreads();
    int node = p * 256 + t;
    if (node < NN) cnt[node] = min(c256[t], SLOT);
}

// ---------------------------------------------------------------- weight pack
__global__ __launch_bounds__(256) void wpack_kernel(const float* __restrict__ W1,
                                                    const float* __restrict__ W2,
                                                    unsigned short* __restrict__ wpk) {
    int m = blockIdx.x;                     // 0..9 = l*2 + s
    int l = m >> 1, s = m & 1;
    const float* W = (s ? W2 : W1) + l * DD * DD;   // [k][n] row-major
    unsigned short* outl = wpk + (size_t)l * 8192;
    for (int idx = threadIdx.x; idx < 512; idx += 256) {
        int nt = idx >> 7, c = (idx >> 6) & 1, lane = idx & 63;
        int n16 = lane & 15, qq = lane >> 4;
        int frag = s * 8 + nt * 2 + c;
        unsigned short* o = outl + ((size_t)frag * 64 + lane) * 8;
#pragma unroll
        for (int j = 0; j < 8; j++) {
            int k = c * 32 + qq * 8 + j;
            o[j] = f2bf(W[k * DD + nt * 16 + n16]);
        }
    }
}

// ---------------------------------------------------------------- x -> bf16
__global__ __launch_bounds__(256) void x2bf_kernel(const float* __restrict__ x,
                                                   unsigned short* __restrict__ xb) {
    int i = blockIdx.x * 256 + threadIdx.x;        // i < N*D/4
    if (i < NN * DD / 4) {
        float4 v = ((const float4*)x)[i];
        ushort4 o;
        o.x = f2bf(v.x); o.y = f2bf(v.y); o.z = f2bf(v.z); o.w = f2bf(v.w);
        ((ushort4*)xb)[i] = o;
    }
}

// ---------------------------------------------------------------- fused layer
// R7: unconditional dual-issue regressed (VALUBusy 50%): gather co-limited by
// VALU instr count (~5/edge) + latency.
// R8/R9 gather decomposition: 8 LANES OWN ONE NODE (lane=(g,i8), i8 = 16B row
// slice). 8 nodes/pass, 2 passes/tile:
//  * NO cross-lane reduce (each lane owns 8 features end-to-end); own-row
//    initializes acc - the 24 shuffle+adds per node are GONE
//  * slot list preloaded 8-at-a-time (1 coalesced srtb read), broadcast
//    in-group by ONE ds_swizzle per slot (swz8<K>, compile-time imm - R8's
//    compile failure was a runtime k in the builtin's imm operand)
//  * uint4 row loads: 1 instr = 8 rows (one per group); chunk bursts 8 loads
//  * ~2.8 instr/edge vs ~5 (R6)
//  * masked slots: cndmask idx->0 BEFORE address formation (garbage-safe),
//    fmk zeroes the contribution; chunks adaptive via wave-max deg
// Tripwires: VGPR<=90, WRITE_SIZE==12.5MB (no spill).
__global__ __launch_bounds__(512, 5) void gin_layer_m(const unsigned short* __restrict__ hbf,
                                                   void* __restrict__ outp,
                                                   const int* __restrict__ cnt,
                                                   const int* __restrict__ srtb,
                                                   const unsigned short* __restrict__ wpk,
                                                   const float* __restrict__ b1,
                                                   const float* __restrict__ b2,
                                                   const float* __restrict__ gamma,
                                                   const float* __restrict__ beta,
                                                   const float* __restrict__ mean,
                                                   const float* __restrict__ var,
                                                   int apply_bn, int out_bf16) {
    __shared__ float tiles[8][16 * TPAD];   // per-wave z/y tile (34816B total)

    const int tid = threadIdx.x;
    const int lane = tid & 63;
    const int wave = tid >> 6;
    const int tile = blockIdx.x * 8 + wave;
    if (tile >= NTILES) return;

    const int q  = lane >> 4;      // quad (MFMA phase)
    const int nl = lane & 15;      // m or n (MFMA phase)
    const int g  = lane >> 3;      // node group 0..7 (gather phase)
    const int i8 = lane & 7;       // 16B row slice (gather phase)
    const int base = tile * 16;
    const uint4* __restrict__ hv4 = (const uint4*)hbf;   // row = 8 x uint4 (128B)
    const short8* __restrict__ wg = (const short8*)wpk;  // 16 frags x 64 lanes x 16B
    float* zT = tiles[wave];

#define UNPK8(Vv, mk) do { \
        acc[0] = fmaf(bflo((Vv).x), (mk), acc[0]); \
        acc[1] = fmaf(bfhi((Vv).x), (mk), acc[1]); \
        acc[2] = fmaf(bflo((Vv).y), (mk), acc[2]); \
        acc[3] = fmaf(bfhi((Vv).y), (mk), acc[3]); \
        acc[4] = fmaf(bflo((Vv).z), (mk), acc[4]); \
        acc[5] = fmaf(bfhi((Vv).z), (mk), acc[5]); \
        acc[6] = fmaf(bflo((Vv).w), (mk), acc[6]); \
        acc[7] = fmaf(bfhi((Vv).w), (mk), acc[7]); \
    } while (0)

    // one chunk = 8 slots x 8 nodes = 64 edges: 8 swizzle-broadcast indices
    // (constant-indexed init list -> registers), 8 uint4 row loads (burst),
    // then 128 unpack-FMAs
#define CHUNK8(sreg, cb) do { \
        const int ixs[8] = { swz8<0>(sreg), swz8<1>(sreg), swz8<2>(sreg), swz8<3>(sreg), \
                             swz8<4>(sreg), swz8<5>(sreg), swz8<6>(sreg), swz8<7>(sreg) }; \
        uint4 Vv[8]; float fmk[8]; \
        _Pragma("unroll") \
        for (int k = 0; k < 8; k++) { \
            bool ok = ((cb) + k < deg); \
            int ix = ok ? ixs[k] : 0; \
            fmk[k] = ok ? 1.f : 0.f; \
            Vv[k] = hv4[(size_t)ix * 8 + i8]; \
        } \
        _Pragma("unroll") \
        for (int k = 0; k < 8; k++) UNPK8(Vv[k], fmk[k]); \
    } while (0)

    // ---------------- gather phase (8 lanes per node) ----------------
#pragma unroll 1
    for (int pass = 0; pass < 2; pass++) {
        const int node = base + pass * 8 + g;
        const int deg = cnt[node];                  // group-uniform
        const int sb = node << 6;
        int s0 = srtb[sb + i8];                     // slots 0..7  (lane i8)
        int s1 = srtb[sb + 8 + i8];                 // slots 8..15
        uint4 ownv = hv4[(size_t)node * 8 + i8];
        int md = deg;                               // wave-max degree
        md = max(md, __shfl_xor(md, 8, 64));
        md = max(md, __shfl_xor(md, 16, 64));
        md = max(md, __shfl_xor(md, 32, 64));
        float acc[8] = { bflo(ownv.x), bfhi(ownv.x), bflo(ownv.y), bfhi(ownv.y),
                         bflo(ownv.z), bfhi(ownv.z), bflo(ownv.w), bfhi(ownv.w) };
        CHUNK8(s0, 0);
        CHUNK8(s1, 8);
        if (md > 16) {
            int s2 = srtb[sb + 16 + i8];
            int s3 = srtb[sb + 24 + i8];
            CHUNK8(s2, 16);
            CHUNK8(s3, 24);
            if (md > 32) {                          // rare (~0.1% of passes)
                int s4 = srtb[sb + 32 + i8];
                int s5 = srtb[sb + 40 + i8];
                int s6 = srtb[sb + 48 + i8];
                int s7 = srtb[sb + 56 + i8];
                CHUNK8(s4, 32);
                CHUNK8(s5, 40);
                CHUNK8(s6, 48);
                CHUNK8(s7, 56);
            }
        }
        const int t = pass * 8 + g;
        float* zp = &zT[t * TPAD + i8 * 8];
        *(float4*)zp = make_float4(acc[0], acc[1], acc[2], acc[3]);
        *(float4*)(zp + 4) = make_float4(acc[4], acc[5], acc[6], acc[7]);
    }
#undef CHUNK8
#undef UNPK8

    // ---------------- epilogue params
    float bias1v[4], bias2v[4], scl[4], shf[4];
#pragma unroll
    for (int nt = 0; nt < 4; nt++) {
        int n = nt * 16 + nl;
        bias1v[nt] = b1[n];
        bias2v[nt] = b2[n];
        if (apply_bn) {
            scl[nt] = gamma[n] * rsqrtf(var[n] + BN_EPS);
            shf[nt] = beta[n] - mean[n] * scl[nt];
        } else { scl[nt] = 1.f; shf[nt] = 0.f; }
    }

    // ---------------- MLP via MFMA (weights from global: L1-resident) ------
    f32x4 accy[4];
#pragma unroll
    for (int nt = 0; nt < 4; nt++) accy[nt] = (f32x4){0.f, 0.f, 0.f, 0.f};

#pragma unroll
    for (int c = 0; c < 2; c++) {
        const float* p = zT + nl * TPAD + c * 32 + q * 8;
        float4 g0 = *(const float4*)p;
        float4 g1 = *(const float4*)(p + 4);
        float f[8] = {g0.x, g0.y, g0.z, g0.w, g1.x, g1.y, g1.z, g1.w};
        short8 ah, al;
#pragma unroll
        for (int j = 0; j < 8; j++) {
            unsigned short hb = f2bf(f[j]);
            ah[j] = (short)hb;
            al[j] = (short)f2bf(f[j] - bf2f(hb));
        }
#pragma unroll
        for (int nt = 0; nt < 4; nt++) {
            short8 bw = wg[(nt * 2 + c) * 64 + lane];
            accy[nt] = __builtin_amdgcn_mfma_f32_16x16x32_bf16(ah, bw, accy[nt], 0, 0, 0);
            accy[nt] = __builtin_amdgcn_mfma_f32_16x16x32_bf16(al, bw, accy[nt], 0, 0, 0);
        }
    }
#pragma unroll
    for (int nt = 0; nt < 4; nt++)
#pragma unroll
        for (int r = 0; r < 4; r++) {
            float y = fmaxf(accy[nt][r] + bias1v[nt], 0.f);
            zT[(q * 4 + r) * TPAD + nt * 16 + nl] = y;
        }

    f32x4 acco[4];
#pragma unroll
    for (int nt = 0; nt < 4; nt++) acco[nt] = (f32x4){0.f, 0.f, 0.f, 0.f};

#pragma unroll
    for (int c = 0; c < 2; c++) {
        const float* p = zT + nl * TPAD + c * 32 + q * 8;
        float4 g0 = *(const float4*)p;
        float4 g1 = *(const float4*)(p + 4);
        float f[8] = {g0.x, g0.y, g0.z, g0.w, g1.x, g1.y, g1.z, g1.w};
        short8 ah, al;
#pragma unroll
        for (int j = 0; j < 8; j++) {
            unsigned short hb = f2bf(f[j]);
            ah[j] = (short)hb;
            al[j] = (short)f2bf(f[j] - bf2f(hb));
        }
#pragma unroll
        for (int nt = 0; nt < 4; nt++) {
            short8 bw = wg[(8 + nt * 2 + c) * 64 + lane];
            acco[nt] = __builtin_amdgcn_mfma_f32_16x16x32_bf16(ah, bw, acco[nt], 0, 0, 0);
            acco[nt] = __builtin_amdgcn_mfma_f32_16x16x32_bf16(al, bw, acco[nt], 0, 0, 0);
        }
    }
    if (out_bf16) {
        unsigned short* ob = (unsigned short*)outp;
#pragma unroll
        for (int nt = 0; nt < 4; nt++)
#pragma unroll
            for (int r = 0; r < 4; r++) {
                float o = acco[nt][r] + bias2v[nt];
                if (apply_bn) o = fmaxf(fmaf(o, scl[nt], shf[nt]), 0.f);
                ob[(base + q * 4 + r) * DD + nt * 16 + nl] = f2bf(o);
            }
    } else {
        float* of = (float*)outp;
#pragma unroll
        for (int nt = 0; nt < 4; nt++)
#pragma unroll
            for (int r = 0; r < 4; r++) {
                float o = acco[nt][r] + bias2v[nt];
                if (apply_bn) o = fmaxf(fmaf(o, scl[nt], shf[nt]), 0.f);
                of[(base + q * 4 + r) * DD + nt * 16 + nl] = o;
            }
    }
}

// ---------------------------------------------------------------- launch
extern "C" void kernel_launch(void* const* d_in, const int* in_sizes, int n_in,
                              void* d_out, int out_size, void* d_ws, size_t ws_size,
                              hipStream_t stream) {
    const float* x     = (const float*)d_in[0];
    const int*   ei    = (const int*)d_in[1];
    const float* W1    = (const float*)d_in[2];
    const float* b1    = (const float*)d_in[3];
    const float* W2    = (const float*)d_in[4];
    const float* b2    = (const float*)d_in[5];
    const float* gamma = (const float*)d_in[6];
    const float* beta  = (const float*)d_in[7];
    const float* mean  = (const float*)d_in[8];
    const float* var   = (const float*)d_in[9];
    float* out = (float*)d_out;

    const int* src = ei;
    const int* dst = ei + EE;

    // workspace (~51.7 MB)
    unsigned short* hb0 = (unsigned short*)d_ws;            // N*64 bf16 (12.8MB)
    unsigned short* hb1 = hb0 + (size_t)NN * DD;            // N*64 bf16 (12.8MB)
    int*            cnt  = (int*)(hb1 + (size_t)NN * DD);   // N (400KB)
    int*            srtb = cnt + NN;                        // N*64 dense (25.6MB)
    unsigned short* wpk  = (unsigned short*)(srtb + (size_t)NN * SLOT); // 5*8192
    // build scratch ALIASED inside hb0 (hb0 first written by x2bf AFTER csr):
    int* pcnt = (int*)d_ws;                                 // NPART
    int* part = pcnt + NPART;                               // NPART*PCAP (~7.2MB)

    hipMemsetAsync(pcnt, 0, NPART * sizeof(int), stream);
    bin2_kernel<<<BIN_BLOCKS, 256, 0, stream>>>(src, dst, pcnt, part);
    wpack_kernel<<<10, 256, 0, stream>>>(W1, W2, wpk);
    csr_kernel<<<NPART, 256, 0, stream>>>(pcnt, part, cnt, srtb);
    x2bf_kernel<<<(NN * DD / 4 + 255) / 256, 256, 0, stream>>>(x, hb0);

    const int grid = (NTILES + 7) / 8;   // 782 blocks, 8 tiles per block (1/wave)
    const unsigned short* hin = hb0;
    for (int l = 0; l < LL; l++) {
        int last = (l == LL - 1);
        void* hout = last ? (void*)out : (void*)((l & 1) ? hb0 : hb1);
        int bn = last ? 0 : 1;
        const float* g  = gamma + (bn ? l * DD : 0);
        const float* be = beta  + (bn ? l * DD : 0);
        const float* mn = mean  + (bn ? l * DD : 0);
        const float* vr = var   + (bn ? l * DD : 0);
        gin_layer_m<<<grid, 512, 0, stream>>>(hin, hout, cnt, srtb,
                                              wpk + (size_t)l * 8192,
                                              b1 + l * DD, b2 + l * DD,
                                              g, be, mn, vr, bn, last ? 0 : 1);
        hin = (const unsigned short*)hout;
    }
}

// Round 10
// 360.137 us; speedup vs baseline: 1.3167x; 1.3167x over previous
//
#include <hip/hip_runtime.h>

#define NN 100000
#define EE 1600000
#define DD 64
#define LL 5
#define BN_EPS 1e-5f
#define SLOT 64
#define NTILES (NN / 16)            // 6250 node-tiles of 16
#define TPAD 68                     // padded z/y row stride (floats)
#define NPART ((NN + 255) / 256)    // 391 partitions of 256 nodes
#define PCAP 4608                   // per-partition edge cap (mean 4092, +8 sigma)
#define BIN_CHUNK 4096
#define BIN_BLOCKS ((EE + BIN_CHUNK - 1) / BIN_CHUNK)   // 391

typedef __attribute__((ext_vector_type(8))) short short8;
typedef __attribute__((ext_vector_type(4))) float f32x4;

static __device__ __forceinline__ unsigned short f2bf(float f) {
    union { float f; unsigned u; } v; v.f = f;
    unsigned u = v.u + 0x7fffu + ((v.u >> 16) & 1u);   // RNE
    return (unsigned short)(u >> 16);
}
static __device__ __forceinline__ float bf2f(unsigned short s) {
    union { unsigned u; float f; } v; v.u = ((unsigned)s) << 16;
    return v.f;
}
// unpack low/high bf16 of a u32 (two packed bf16) to f32
static __device__ __forceinline__ float bflo(unsigned u) {
    union { unsigned x; float f; } v; v.x = u << 16; return v.f;
}
static __device__ __forceinline__ float bfhi(unsigned u) {
    union { unsigned x; float f; } v; v.x = u & 0xffff0000u; return v.f;
}

// ---------------------------------------------------------------- pass 1: bin edges
__global__ __launch_bounds__(256) void bin2_kernel(const int* __restrict__ src,
                                                   const int* __restrict__ dst,
                                                   int* __restrict__ pcnt,
                                                   int* __restrict__ part) {
    __shared__ int hist[NPART];
    __shared__ int basep[NPART];
    const int t = threadIdx.x;
    const int e0 = blockIdx.x * BIN_CHUNK;
    const int e1 = min(e0 + BIN_CHUNK, EE);

    for (int i = t; i < NPART; i += 256) hist[i] = 0;
    __syncthreads();
    for (int e = e0 + t; e < e1; e += 256)
        atomicAdd(&hist[dst[e] >> 8], 1);
    __syncthreads();
    for (int i = t; i < NPART; i += 256) {
        int c = hist[i];
        basep[i] = (c > 0) ? atomicAdd(&pcnt[i], c) : 0;
        hist[i] = 0;                           // reuse as cursor
    }
    __syncthreads();
    for (int e = e0 + t; e < e1; e += 256) {
        int d = dst[e];
        int s = src[e];
        int p = d >> 8;
        int pos = basep[p] + atomicAdd(&hist[p], 1);
        if (pos < PCAP) part[p * PCAP + pos] = ((d & 255) << 17) | s;
    }
}

// ---------------------------------------------------------------- pass 2: per-partition packed CSR
// R6-slim (proven): no ent/lsrc LDS staging. Both passes read part[] straight
// from global (each block re-reads its OWN 18KB partition back-to-back ->
// L2-hot) and scatter psrc directly.
// psrc[p*PCAP + pos]: src lists node-major within partition.
// meta[node] = ((p*PCAP + base) << 7) | deg
__global__ __launch_bounds__(256) void csr_kernel(const int* __restrict__ pcnt,
                                                  const int* __restrict__ part,
                                                  int* __restrict__ meta,
                                                  int* __restrict__ psrc) {
    __shared__ int c256[256];
    __shared__ int scanb[256];
    __shared__ int cur[256];

    const int p = blockIdx.x;
    const int t = threadIdx.x;
    const int M = min(pcnt[p], PCAP);

    c256[t] = 0;
    __syncthreads();
    for (int i = t; i < M; i += 256)
        atomicAdd(&c256[part[p * PCAP + i] >> 17], 1);
    __syncthreads();
    int v = c256[t];
    scanb[t] = v;
    __syncthreads();
    for (int off = 1; off < 256; off <<= 1) {
        int a = (t >= off) ? scanb[t - off] : 0;
        __syncthreads();
        scanb[t] += a;
        __syncthreads();
    }
    const int bse = scanb[t] - v;     // exclusive prefix
    cur[t] = bse;
    __syncthreads();
    for (int i = t; i < M; i += 256) {
        int e = part[p * PCAP + i];            // L2-hot re-read
        int pos = atomicAdd(&cur[e >> 17], 1);
        psrc[p * PCAP + pos] = e & 0x1FFFF;    // direct scatter (18KB window)
    }
    int node = p * 256 + t;
    if (node < NN) {
        int deg = min(v, SLOT);
        meta[node] = ((p * PCAP + bse) << 7) | deg;
    }
}

// ---------------------------------------------------------------- weight pack
__global__ __launch_bounds__(256) void wpack_kernel(const float* __restrict__ W1,
                                                    const float* __restrict__ W2,
                                                    unsigned short* __restrict__ wpk) {
    int m = blockIdx.x;                     // 0..9 = l*2 + s
    int l = m >> 1, s = m & 1;
    const float* W = (s ? W2 : W1) + l * DD * DD;   // [k][n] row-major
    unsigned short* outl = wpk + (size_t)l * 8192;
    for (int idx = threadIdx.x; idx < 512; idx += 256) {
        int nt = idx >> 7, c = (idx >> 6) & 1, lane = idx & 63;
        int n16 = lane & 15, qq = lane >> 4;
        int frag = s * 8 + nt * 2 + c;
        unsigned short* o = outl + ((size_t)frag * 64 + lane) * 8;
#pragma unroll
        for (int j = 0; j < 8; j++) {
            int k = c * 32 + qq * 8 + j;
            o[j] = f2bf(W[k * DD + nt * 16 + n16]);
        }
    }
}

// ---------------------------------------------------------------- x -> bf16
__global__ __launch_bounds__(256) void x2bf_kernel(const float* __restrict__ x,
                                                   unsigned short* __restrict__ xb) {
    int i = blockIdx.x * 256 + threadIdx.x;        // i < N*D/4
    if (i < NN * DD / 4) {
        float4 v = ((const float4*)x)[i];
        ushort4 o;
        o.x = f2bf(v.x); o.y = f2bf(v.y); o.z = f2bf(v.z); o.w = f2bf(v.w);
        ((ushort4*)xb)[i] = o;
    }
}

// ---------------------------------------------------------------- fused layer
// R10 = R3's layer VERBATIM (best measured: 47.5us, VGPR 40, no spill).
// Session ledger: R4 SWP pipeline -9%, R5 occupancy clamp -24%, R7 dual-issue
// -15%, R8/R9 8-lane decomposition -68% (spill). The proven structure:
//  * bf16 h rows (128B, halves bytes vs f32 - the one big win, R3)
//  * meta[16 nodes] in ONE load + shfl broadcast; psrc slot list depth-1
//    prefetched under current node's FMAs
//  * deg>16 uniform-branch skip of slots 16..31 (saves 29% loads)
//  * wlds LDS weight stage (16KB amortized over 8 waves)
__global__ __launch_bounds__(512, 5) void gin_layer_m(const unsigned short* __restrict__ hbf,
                                                   void* __restrict__ outp,
                                                   const int* __restrict__ meta,
                                                   const int* __restrict__ psrc,
                                                   const unsigned short* __restrict__ wpk,
                                                   const float* __restrict__ b1,
                                                   const float* __restrict__ b2,
                                                   const float* __restrict__ gamma,
                                                   const float* __restrict__ beta,
                                                   const float* __restrict__ mean,
                                                   const float* __restrict__ var,
                                                   int apply_bn, int out_bf16) {
    __shared__ short8 wlds[16 * 64];        // 16KB packed weights (both stages)
    __shared__ float tiles[8][16 * TPAD];   // per-wave z/y tile (34816B)

    const int tid = threadIdx.x;
    {   // cooperative weight stage (16KB = 1024 float4, 512 threads x 2)
        const float4* wg = (const float4*)wpk;
        float4* wl = (float4*)wlds;
#pragma unroll
        for (int k = 0; k < 2; k++) wl[tid + 512 * k] = wg[tid + 512 * k];
    }
    __syncthreads();

    const int lane = tid & 63;
    const int wave = tid >> 6;
    const int tile = blockIdx.x * 8 + wave;
    if (tile >= NTILES) return;

    const int q  = lane >> 4;      // edge-group (gather) / quad (MFMA)
    const int nl = lane & 15;      // 8B slice (gather) / m or n (MFMA)
    const int base = tile * 16;
    const uint2* __restrict__ hv = (const uint2*)hbf;   // row = 16 x uint2 (128B)
    float* zT = tiles[wave];

    float bias1v[4], bias2v[4], scl[4], shf[4];
#pragma unroll
    for (int nt = 0; nt < 4; nt++) {
        int n = nt * 16 + nl;
        bias1v[nt] = b1[n];
        bias2v[nt] = b2[n];
        if (apply_bn) {
            scl[nt] = gamma[n] * rsqrtf(var[n] + BN_EPS);
            shf[nt] = beta[n] - mean[n] * scl[nt];
        } else { scl[nt] = 1.f; shf[nt] = 0.f; }
    }

    // unpack-FMA: 4 bf16 in a uint2 -> acc (features 4nl..4nl+3)
#define UFMA(acc, rv, mk) do { \
        (acc).x = fmaf(bflo((rv).x), (mk), (acc).x); \
        (acc).y = fmaf(bfhi((rv).x), (mk), (acc).y); \
        (acc).z = fmaf(bflo((rv).y), (mk), (acc).z); \
        (acc).w = fmaf(bfhi((rv).y), (mk), (acc).w); \
    } while (0)

    // ---------------- gather phase ----------------
    // 16 node headers in one load (lane nl holds meta of node base+nl)
    const int mv = meta[base + nl];

    // prologue: node 0 slot values
    int mm0 = __shfl(mv, 0, 64);
    int deg = mm0 & 127;
    int eidx = (deg > 0) ? psrc[(mm0 >> 7) + min(lane, deg - 1)] : 0;

#pragma unroll 1
    for (int t = 0; t < 16; t++) {
        uint2 V[8];
        const bool hi = (deg > 16);           // wave-uniform
        // first-half loads: slots 0..15 (4 rows per lane-group)
#pragma unroll
        for (int u = 0; u < 4; u++) {
            int e = 4 * u + q;
            int s = __shfl(eidx, (e < deg) ? e : 0, 64);
            V[u] = hv[s * 16 + nl];
        }
        if (hi) {                             // slots 16..31 only when needed
#pragma unroll
            for (int u = 0; u < 4; u++) {
                int e = 16 + 4 * u + q;
                int s = __shfl(eidx, (e < deg) ? e : 0, 64);
                V[4 + u] = hv[s * 16 + nl];
            }
        }
        // own row (independent, used after reduce -> latency hidden)
        uint2 ownr = hv[(base + t) * 16 + nl];
        // prefetch next node's slot values under this node's FMAs
        int deg_n = deg, eidx_n = eidx;
        if (t < 15) {
            int m = __shfl(mv, t + 1, 64);
            deg_n = m & 127;
            eidx_n = (deg_n > 0) ? psrc[(m >> 7) + min(lane, deg_n - 1)] : 0;
        }

        float4 acc = make_float4(0.f, 0.f, 0.f, 0.f);
#pragma unroll
        for (int u = 0; u < 4; u++) {
            float mk = (4 * u + q < deg) ? 1.f : 0.f;
            UFMA(acc, V[u], mk);
        }
        if (hi) {
#pragma unroll
            for (int u = 0; u < 4; u++) {
                float mk = (16 + 4 * u + q < deg) ? 1.f : 0.f;
                UFMA(acc, V[4 + u], mk);
            }
            for (int jj = 32; jj < deg; jj += 16) {   // rare tail (deg > 32)
#pragma unroll
                for (int u = 0; u < 4; u++) {
                    int e = jj + 4 * u + q;
                    int s = __shfl(eidx, (e < deg) ? e : 0, 64);
                    uint2 tv = hv[s * 16 + nl];
                    float mk = (e < deg) ? 1.f : 0.f;
                    UFMA(acc, tv, mk);
                }
            }
        }
        // reduce across the 4 q-groups
        acc.x += __shfl_xor(acc.x, 16, 64);
        acc.y += __shfl_xor(acc.y, 16, 64);
        acc.z += __shfl_xor(acc.z, 16, 64);
        acc.w += __shfl_xor(acc.w, 16, 64);
        acc.x += __shfl_xor(acc.x, 32, 64);
        acc.y += __shfl_xor(acc.y, 32, 64);
        acc.z += __shfl_xor(acc.z, 32, 64);
        acc.w += __shfl_xor(acc.w, 32, 64);
        acc.x += bflo(ownr.x); acc.y += bfhi(ownr.x);
        acc.z += bflo(ownr.y); acc.w += bfhi(ownr.y);
        if (q == 0) *(float4*)&zT[t * TPAD + 4 * nl] = acc;

        deg = deg_n; eidx = eidx_n;
    }
#undef UFMA

    // ---------------- MLP via MFMA ----------------
    f32x4 accy[4];
#pragma unroll
    for (int nt = 0; nt < 4; nt++) accy[nt] = (f32x4){0.f, 0.f, 0.f, 0.f};

#pragma unroll
    for (int c = 0; c < 2; c++) {
        const float* p = zT + nl * TPAD + c * 32 + q * 8;
        float4 g0 = *(const float4*)p;
        float4 g1 = *(const float4*)(p + 4);
        float f[8] = {g0.x, g0.y, g0.z, g0.w, g1.x, g1.y, g1.z, g1.w};
        short8 ah, al;
#pragma unroll
        for (int j = 0; j < 8; j++) {
            unsigned short hb = f2bf(f[j]);
            ah[j] = (short)hb;
            al[j] = (short)f2bf(f[j] - bf2f(hb));
        }
#pragma unroll
        for (int nt = 0; nt < 4; nt++) {
            short8 bw = wlds[(nt * 2 + c) * 64 + lane];
            accy[nt] = __builtin_amdgcn_mfma_f32_16x16x32_bf16(ah, bw, accy[nt], 0, 0, 0);
            accy[nt] = __builtin_amdgcn_mfma_f32_16x16x32_bf16(al, bw, accy[nt], 0, 0, 0);
        }
    }
#pragma unroll
    for (int nt = 0; nt < 4; nt++)
#pragma unroll
        for (int r = 0; r < 4; r++) {
            float y = fmaxf(accy[nt][r] + bias1v[nt], 0.f);
            zT[(q * 4 + r) * TPAD + nt * 16 + nl] = y;
        }

    f32x4 acco[4];
#pragma unroll
    for (int nt = 0; nt < 4; nt++) acco[nt] = (f32x4){0.f, 0.f, 0.f, 0.f};

#pragma unroll
    for (int c = 0; c < 2; c++) {
        const float* p = zT + nl * TPAD + c * 32 + q * 8;
        float4 g0 = *(const float4*)p;
        float4 g1 = *(const float4*)(p + 4);
        float f[8] = {g0.x, g0.y, g0.z, g0.w, g1.x, g1.y, g1.z, g1.w};
        short8 ah, al;
#pragma unroll
        for (int j = 0; j < 8; j++) {
            unsigned short hb = f2bf(f[j]);
            ah[j] = (short)hb;
            al[j] = (short)f2bf(f[j] - bf2f(hb));
        }
#pragma unroll
        for (int nt = 0; nt < 4; nt++) {
            short8 bw = wlds[(8 + nt * 2 + c) * 64 + lane];
            acco[nt] = __builtin_amdgcn_mfma_f32_16x16x32_bf16(ah, bw, acco[nt], 0, 0, 0);
            acco[nt] = __builtin_amdgcn_mfma_f32_16x16x32_bf16(al, bw, acco[nt], 0, 0, 0);
        }
    }
    if (out_bf16) {
        unsigned short* ob = (unsigned short*)outp;
#pragma unroll
        for (int nt = 0; nt < 4; nt++)
#pragma unroll
            for (int r = 0; r < 4; r++) {
                float o = acco[nt][r] + bias2v[nt];
                if (apply_bn) o = fmaxf(fmaf(o, scl[nt], shf[nt]), 0.f);
                ob[(base + q * 4 + r) * DD + nt * 16 + nl] = f2bf(o);
            }
    } else {
        float* of = (float*)outp;
#pragma unroll
        for (int nt = 0; nt < 4; nt++)
#pragma unroll
            for (int r = 0; r < 4; r++) {
                float o = acco[nt][r] + bias2v[nt];
                if (apply_bn) o = fmaxf(fmaf(o, scl[nt], shf[nt]), 0.f);
                of[(base + q * 4 + r) * DD + nt * 16 + nl] = o;
            }
    }
}

// ---------------------------------------------------------------- launch
extern "C" void kernel_launch(void* const* d_in, const int* in_sizes, int n_in,
                              void* d_out, int out_size, void* d_ws, size_t ws_size,
                              hipStream_t stream) {
    const float* x     = (const float*)d_in[0];
    const int*   ei    = (const int*)d_in[1];
    const float* W1    = (const float*)d_in[2];
    const float* b1    = (const float*)d_in[3];
    const float* W2    = (const float*)d_in[4];
    const float* b2    = (const float*)d_in[5];
    const float* gamma = (const float*)d_in[6];
    const float* beta  = (const float*)d_in[7];
    const float* mean  = (const float*)d_in[8];
    const float* var   = (const float*)d_in[9];
    float* out = (float*)d_out;

    const int* src = ei;
    const int* dst = ei + EE;

    // workspace (~33.5 MB)
    unsigned short* hb0 = (unsigned short*)d_ws;            // N*64 bf16 (12.8MB)
    unsigned short* hb1 = hb0 + (size_t)NN * DD;            // N*64 bf16 (12.8MB)
    int*            meta = (int*)(hb1 + (size_t)NN * DD);   // N   packed (base<<7)|deg
    int*            psrc = meta + NN;                       // NPART*PCAP (7.2MB)
    unsigned short* wpk  = (unsigned short*)(psrc + NPART * PCAP + 64); // 5*8192 shorts
    // build scratch ALIASED inside hb0 (hb0 first written by x2bf AFTER csr):
    int* pcnt = (int*)d_ws;                                 // NPART
    int* part = pcnt + NPART;                               // NPART*PCAP (~7.2MB)

    hipMemsetAsync(pcnt, 0, NPART * sizeof(int), stream);
    bin2_kernel<<<BIN_BLOCKS, 256, 0, stream>>>(src, dst, pcnt, part);
    wpack_kernel<<<10, 256, 0, stream>>>(W1, W2, wpk);
    csr_kernel<<<NPART, 256, 0, stream>>>(pcnt, part, meta, psrc);
    x2bf_kernel<<<(NN * DD / 4 + 255) / 256, 256, 0, stream>>>(x, hb0);

    const int grid = (NTILES + 7) / 8;   // 782 blocks, 8 tiles per block (1/wave)
    const unsigned short* hin = hb0;
    for (int l = 0; l < LL; l++) {
        int last = (l == LL - 1);
        void* hout = last ? (void*)out : (void*)((l & 1) ? hb0 : hb1);
        int bn = last ? 0 : 1;
        const float* g  = gamma + (bn ? l * DD : 0);
        const float* be = beta  + (bn ? l * DD : 0);
        const float* mn = mean  + (bn ? l * DD : 0);
        const float* vr = var   + (bn ? l * DD : 0);
        gin_layer_m<<<grid, 512, 0, stream>>>(hin, hout, meta, psrc,
                                              wpk + (size_t)l * 8192,
                                              b1 + l * DD, b2 + l * DD,
                                              g, be, mn, vr, bn, last ? 0 : 1);
        hin = (const unsigned short*)hout;
    }
}